// Round 10
// baseline (221.127 us; speedup 1.0000x reference)
//
#include <hip/hip_runtime.h>
#include <math.h>

// Problem constants (reference: B=4, N=8192, points are [B,N,3] fp32)
#define BATCH 4
#define NPTS 8192
#define BN (BATCH * NPTS)
#define NZB 16                 // 4 searches x 4 batches
#define QN (NZB * NPTS)        // 131072 total queries
#define TAU 1.0e-2f            // flag margin >= 2*eps (eps ~1.5e-3 analytic)

// Workspace: [0] double acc | [8] uint ticket | [64] int idx_all[QN] (512KB)
//            [+512K] float part_d[SPL][QN] (SPL*512KB)
//            [after] ushort bpack[QN][16]  (4MB)   total(SPL=32)=21.496MB

using frag_ab = __attribute__((ext_vector_type(8))) short;   // 8 bf16
using frag_cd = __attribute__((ext_vector_type(4))) float;   // 4 fp32

__device__ __forceinline__ void pick_ab(int z, const float* pw, const float* pp,
                                        const float* tw, const float* tp,
                                        const float** qa, const float** cb) {
  if (z == 0)      { *qa = pw; *cb = pp; }
  else if (z == 1) { *qa = pp; *cb = pw; }
  else if (z == 2) { *qa = tw; *cb = tp; }
  else             { *qa = tp; *cb = tw; }
}

__device__ __forceinline__ unsigned short f2bf(float x) {   // RNE
  unsigned int u = __float_as_uint(x);
  u += 0x7fffu + ((u >> 16) & 1u);
  return (unsigned short)(u >> 16);
}
__device__ __forceinline__ float bf2f(unsigned short h) {
  return __uint_as_float(((unsigned int)h) << 16);
}

// ---------------------------------------------------------------------------
// Pass 0: pack candidates. Per candidate 16 bf16 K-slots (32B):
//  B[k] = [bhx,bhy,bhz, bhx,bhy,bhz, blx,bly,blz, blx,bly,blz, b2h,b2l, 0,0]
// Paired with A = [-2ahx,-2ahy,-2ahz,-2alx,-2aly,-2alz,
//                  -2ahx,-2ahy,-2ahz,-2alx,-2aly,-2alz, 1,1, 0,0]
// => sum_k A*B = -2(ah+al).(bh+bl) + b2h+b2l  (all 4 cross terms present).
// ---------------------------------------------------------------------------
__global__ __launch_bounds__(256) void pack_kernel(
    const float* __restrict__ pw, const float* __restrict__ pp,
    const float* __restrict__ tw, const float* __restrict__ tp,
    unsigned short* __restrict__ bpack) {
  const int g = blockIdx.x * 256 + threadIdx.x;   // [0, QN)
  const int zb = g >> 13;
  const int n = g & (NPTS - 1);
  const int z = zb >> 2;
  const int b = zb & 3;
  const float* qa;
  const float* cb;
  pick_ab(z, pw, pp, tw, tp, &qa, &cb);

  const float* c = cb + ((size_t)b * NPTS + n) * 3;
  const float bx = c[0], by = c[1], bz = c[2];
  unsigned short bh[3], bl[3];
  const float bf[3] = {bx, by, bz};
  #pragma unroll
  for (int d = 0; d < 3; ++d) {
    bh[d] = f2bf(bf[d]);
    bl[d] = f2bf(bf[d] - bf2f(bh[d]));
  }
  const float b2 = fmaf(bx, bx, fmaf(by, by, bz * bz));
  const unsigned short b2h = f2bf(b2);
  const unsigned short b2l = f2bf(b2 - bf2f(b2h));

  unsigned short v[16] = {bh[0], bh[1], bh[2], bh[0], bh[1], bh[2],
                          bl[0], bl[1], bl[2], bl[0], bl[1], bl[2],
                          b2h, b2l, 0, 0};
  uint4* dst = (uint4*)(bpack + (size_t)g * 16);
  const uint4* src = (const uint4*)v;
  dst[0] = src[0];
  dst[1] = src[1];
}

// ---------------------------------------------------------------------------
// Pass 1: MFMA approx-min scan. Block 256 (4 waves) x (256 queries, one
// candidate slice, one zb). Wave: 4 query-tiles of 16, A-frags in regs;
// B staged in LDS (xor-swizzled 16B granules to spread bank windows);
// per 16x16 tile: 1 MFMA (C=0) + 4 fmin. Verified layouts:
//   A[m=lane&15][k=quad*8+j] (m120); D col=lane&15,row=quad*4+reg (m89/91).
// Quads 2,3 get zero A-frags -> K slots 16..31 contribute nothing.
// grid = (NPTS/256=32, SPL, NZB).
// ---------------------------------------------------------------------------
template <int SPL>
__global__ __launch_bounds__(256, 4) void nn_mfma_scan(
    const float* __restrict__ pw, const float* __restrict__ pp,
    const float* __restrict__ tw, const float* __restrict__ tp,
    const unsigned short* __restrict__ bpack, float* __restrict__ part_d) {
  constexpr int SLICE = NPTS / SPL;
  constexpr int NCT = SLICE / 16;          // candidate tiles per slice
  __shared__ unsigned short lds_b[SLICE * 16];   // SLICE*32B

  const int zb = blockIdx.z;
  const int z = zb >> 2;
  const int b = zb & 3;
  const float* qa;
  const float* cb;
  pick_ab(z, pw, pp, tw, tp, &qa, &cb);
  (void)cb;

  const int tid = threadIdx.x;

  // Stage packed B slice into LDS with xor swizzle on 16B granules.
  {
    const uint4* src =
        (const uint4*)(bpack + ((size_t)zb * NPTS + blockIdx.y * SLICE) * 16);
    uint4* dst = (uint4*)lds_b;
    for (int i = tid; i < SLICE * 2; i += 256) {
      const int pg = i ^ ((i >> 3) & 6);
      dst[pg] = src[i];
    }
  }
  __syncthreads();

  const int wv = tid >> 6;
  const int lane = tid & 63;
  const int quad = lane >> 4;
  const int col = lane & 15;
  const int qbase = blockIdx.x * 256 + wv * 64;

  // Build 4 A-frags (queries qbase+qt*16+col as row m=col).
  frag_ab A[4];
  #pragma unroll
  for (int qt = 0; qt < 4; ++qt) {
    const int n = qbase + qt * 16 + col;
    const float* q = qa + ((size_t)b * NPTS + n) * 3;
    unsigned short h[3], l[3];
    #pragma unroll
    for (int d = 0; d < 3; ++d) {
      const float a = q[d];
      const unsigned short ah = f2bf(a);
      const unsigned short al = f2bf(a - bf2f(ah));
      h[d] = f2bf(-2.0f * bf2f(ah));   // exact: scale by -2 in bf16
      l[d] = f2bf(-2.0f * bf2f(al));
    }
    const short ONE = (short)0x3F80;   // bf16 1.0
    frag_ab q0, q1;
    q0[0] = (short)h[0]; q0[1] = (short)h[1]; q0[2] = (short)h[2];
    q0[3] = (short)l[0]; q0[4] = (short)l[1]; q0[5] = (short)l[2];
    q0[6] = (short)h[0]; q0[7] = (short)h[1];
    q1[0] = (short)h[2]; q1[1] = (short)l[0]; q1[2] = (short)l[1];
    q1[3] = (short)l[2]; q1[4] = ONE;        q1[5] = ONE;
    q1[6] = 0;           q1[7] = 0;
    frag_ab az;
    #pragma unroll
    for (int j = 0; j < 8; ++j) az[j] = 0;
    A[qt] = (quad == 0) ? q0 : (quad == 1) ? q1 : az;
  }

  float dmin[4][4];
  #pragma unroll
  for (int qt = 0; qt < 4; ++qt)
    #pragma unroll
    for (int r = 0; r < 4; ++r) dmin[qt][r] = INFINITY;

  const frag_ab* lb = (const frag_ab*)lds_b;
  const int half = quad & 1;               // quads 2,3: A=0, B irrelevant

  for (int ct = 0; ct < NCT; ++ct) {
    const int g = (ct * 16 + col) * 2 + half;
    const frag_ab Bf = lb[g ^ ((g >> 3) & 6)];
    #pragma unroll
    for (int qt = 0; qt < 4; ++qt) {
      frag_cd cfr = {0.0f, 0.0f, 0.0f, 0.0f};
      cfr = __builtin_amdgcn_mfma_f32_16x16x32_bf16(A[qt], Bf, cfr, 0, 0, 0);
      #pragma unroll
      for (int r = 0; r < 4; ++r) dmin[qt][r] = fminf(dmin[qt][r], cfr[r]);
    }
  }

  // Reduce over the 16 cols (same quad holds same query rows).
  #pragma unroll
  for (int off = 1; off < 16; off <<= 1)
    #pragma unroll
    for (int qt = 0; qt < 4; ++qt)
      #pragma unroll
      for (int r = 0; r < 4; ++r)
        dmin[qt][r] = fminf(dmin[qt][r], __shfl_xor(dmin[qt][r], off));

  if (col == 0) {
    #pragma unroll
    for (int qt = 0; qt < 4; ++qt)
      #pragma unroll
      for (int r = 0; r < 4; ++r) {
        const int m = qbase + qt * 16 + quad * 4 + r;
        part_d[(size_t)blockIdx.y * QN + (size_t)zb * NPTS + m] = dmin[qt][r];
      }
  }
}

// ---------------------------------------------------------------------------
// Pass 2: merge + flag + exact fp32 rescan. Block 1024 (16 waves) covers 64
// queries. Flag every split with approx-min <= m_tilde + TAU (provably
// contains the true argmin); rescan flagged slices in exact fp32 with
// lexicographic (d, index) first-min == jnp.argmin. Zeroes acc+ticket.
// ---------------------------------------------------------------------------
template <int SPL>
__global__ __launch_bounds__(1024) void nn_merge_flag_rescan(
    const float* __restrict__ pw, const float* __restrict__ pp,
    const float* __restrict__ tw, const float* __restrict__ tp,
    const float* __restrict__ part_d, int* __restrict__ idx_all,
    double* __restrict__ acc, unsigned int* __restrict__ ticket) {
  constexpr int SLICE = NPTS / SPL;
  constexpr int NIT = SLICE / 64;
  __shared__ float sm[SPL][64];

  if (blockIdx.x == 0 && threadIdx.x == 0) { *acc = 0.0; *ticket = 0u; }

  const int tid = threadIdx.x;
  const int wv = tid >> 6;
  const int lane = tid & 63;
  const int qid0 = blockIdx.x * 64;

  for (int s = wv; s < SPL; s += 16)
    sm[s][lane] = part_d[(size_t)s * QN + qid0 + lane];
  __syncthreads();

  const int zb = qid0 >> 13;
  const int z = zb >> 2;
  const int b = zb & 3;
  const float* qa;
  const float* cb;
  pick_ab(z, pw, pp, tw, tp, &qa, &cb);
  const float* qb0 = qa + (size_t)b * NPTS * 3;
  const float* cbb = cb + (size_t)b * NPTS * 3;
  const int n0 = qid0 & (NPTS - 1);

  #pragma unroll
  for (int j = 0; j < 4; ++j) {
    const int lq = wv * 4 + j;
    const float* q = qb0 + (size_t)(n0 + lq) * 3;   // wave-uniform
    const float qx = -2.0f * q[0];
    const float qy = -2.0f * q[1];
    const float qz = -2.0f * q[2];

    const float sv = (lane < SPL) ? sm[lane][lq] : INFINITY;
    float mt = sv;
    #pragma unroll
    for (int off = 32; off > 0; off >>= 1) mt = fminf(mt, __shfl_xor(mt, off));
    unsigned long long flags = __ballot(sv <= mt + TAU);

    float bd = INFINITY;
    int bi = 0x7fffffff;
    while (flags) {
      const int s = __ffsll((long long)flags) - 1;   // ascending split order
      flags &= flags - 1;
      for (int it = 0; it < NIT; ++it) {
        const int m = s * SLICE + it * 64 + lane;    // per-lane increasing m
        const float* c = cbb + (size_t)m * 3;
        const float bx = c[0], by = c[1], bz = c[2];
        const float b2 = fmaf(bx, bx, fmaf(by, by, bz * bz));
        const float dd = fmaf(qx, bx, fmaf(qy, by, fmaf(qz, bz, b2)));
        if (dd < bd) { bd = dd; bi = m; }            // strict <: first-min
      }
    }
    #pragma unroll
    for (int off = 32; off > 0; off >>= 1) {
      const float od = __shfl_xor(bd, off);
      const int oi = __shfl_xor(bi, off);
      if (od < bd || (od == bd && oi < bi)) { bd = od; bi = oi; }
    }
    if (lane == 0) idx_all[qid0 + lq] = bi;
  }
}

// ---------------------------------------------------------------------------
// Pass 3 (R9-proven): loss + fused finalize via return-value-ordered atomics.
// loss = 0.25 * (sum of 4 squared-norm sums) / (B*N)
// ---------------------------------------------------------------------------
__device__ __forceinline__ float3 ld3(const float* __restrict__ p, int i) {
  const float* q = p + (size_t)i * 3;
  return make_float3(q[0], q[1], q[2]);
}

__device__ __forceinline__ float diff_nrm2(float3 a1, float3 a2, float3 b1, float3 b2) {
  const float x = (a1.x - a2.x) - (b1.x - b2.x);
  const float y = (a1.y - a2.y) - (b1.y - b2.y);
  const float z = (a1.z - a2.z) - (b1.z - b2.z);
  return fmaf(x, x, fmaf(y, y, z * z));
}

__global__ __launch_bounds__(256) void loss_final_kernel(
    const float* __restrict__ pw, const float* __restrict__ pp,
    const float* __restrict__ tw, const float* __restrict__ tp,
    const int* __restrict__ ipw, const int* __restrict__ itw,
    const int* __restrict__ ipp, const int* __restrict__ itp,
    const int* __restrict__ idx_all, double* __restrict__ acc,
    unsigned int* __restrict__ ticket, float* __restrict__ out) {
  __shared__ double sd[4];

  const int gid = blockIdx.x * 256 + threadIdx.x;  // [0, B*N)
  const int term = blockIdx.y;
  const int b = gid >> 13;
  const int n = gid & (NPTS - 1);
  const int base = b * NPTS;

  const float* PW = pw + (size_t)base * 3;
  const float* PP = pp + (size_t)base * 3;
  const float* TW = tw + (size_t)base * 3;
  const float* TP = tp + (size_t)base * 3;
  const int* I1P = idx_all + (0 * BATCH + b) * NPTS;
  const int* I2P = idx_all + (1 * BATCH + b) * NPTS;
  const int* I1T = idx_all + (2 * BATCH + b) * NPTS;
  const int* I2T = idx_all + (3 * BATCH + b) * NPTS;

  float sv;
  if (term == 0) {
    const int j = ipw[base + n];
    sv = diff_nrm2(ld3(PP, I1P[n]), ld3(PW, n), ld3(TP, I1T[j]), ld3(TW, j));
  } else if (term == 1) {
    const int k = itw[base + n];
    sv = diff_nrm2(ld3(PP, I1P[k]), ld3(PW, k), ld3(TP, I1T[n]), ld3(TW, n));
  } else if (term == 2) {
    const int j = ipp[base + n];
    sv = diff_nrm2(ld3(PP, n), ld3(PW, I2P[n]), ld3(TP, j), ld3(TW, I2T[j]));
  } else {
    const int k = itp[base + n];
    sv = diff_nrm2(ld3(PP, k), ld3(PW, I2P[k]), ld3(TP, n), ld3(TW, I2T[n]));
  }

  double ds = (double)sv;
  #pragma unroll
  for (int o = 32; o > 0; o >>= 1) ds += __shfl_down(ds, o, 64);
  if ((threadIdx.x & 63) == 0) sd[threadIdx.x >> 6] = ds;
  __syncthreads();

  if (threadIdx.x == 0) {
    const double bsum = sd[0] + sd[1] + sd[2] + sd[3];
    const double old = atomicAdd(acc, bsum);
    const unsigned int inc = 1u + (unsigned int)(((unsigned long long)
                             __double_as_longlong(old)) & 0ull);
    const unsigned int total = gridDim.x * gridDim.y;   // 512
    const unsigned int t = atomicAdd(ticket, inc);
    if (t == total - 1u) {
      const double fin = atomicAdd(acc, 0.0);
      out[0] = (float)(0.25 * fin / (double)BN);
    }
  }
}

// ---------------------------------------------------------------------------
template <int SPL>
static void run_pipeline(const float* pw, const float* pp, const float* tw,
                         const float* tp, const int* ipw, const int* itw,
                         const int* ipp, const int* itp, char* ws, float* out,
                         hipStream_t stream) {
  double* acc = (double*)ws;
  unsigned int* ticket = (unsigned int*)(ws + 8);
  int* idx_all = (int*)(ws + 64);
  float* part_d = (float*)(ws + 64 + (size_t)QN * 4);
  unsigned short* bpack =
      (unsigned short*)(ws + 64 + (size_t)QN * 4 + (size_t)SPL * QN * 4);

  pack_kernel<<<QN / 256, 256, 0, stream>>>(pw, pp, tw, tp, bpack);

  dim3 grid_scan(NPTS / 256, SPL, NZB);
  nn_mfma_scan<SPL><<<grid_scan, 256, 0, stream>>>(pw, pp, tw, tp, bpack,
                                                   part_d);
  nn_merge_flag_rescan<SPL><<<QN / 64, 1024, 0, stream>>>(
      pw, pp, tw, tp, part_d, idx_all, acc, ticket);

  dim3 grid_loss(BN / 256, 4);
  loss_final_kernel<<<grid_loss, 256, 0, stream>>>(
      pw, pp, tw, tp, ipw, itw, ipp, itp, idx_all, acc, ticket, out);
}

extern "C" void kernel_launch(void* const* d_in, const int* in_sizes, int n_in,
                              void* d_out, int out_size, void* d_ws, size_t ws_size,
                              hipStream_t stream) {
  const float* pw = (const float*)d_in[0];
  const float* pp = (const float*)d_in[1];
  const float* tw = (const float*)d_in[2];
  const float* tp = (const float*)d_in[3];
  const int* ipw = (const int*)d_in[4];
  const int* itw = (const int*)d_in[5];
  const int* ipp = (const int*)d_in[6];
  const int* itp = (const int*)d_in[7];
  char* ws = (char*)d_ws;
  float* out = (float*)d_out;

  // need(SPL) = 64 + idx(512K) + part_d(SPL*512K) + bpack(4MB)
  const size_t base_need = 64 + (size_t)QN * 4 + (size_t)QN * 32;
  const size_t per_spl = (size_t)QN * 4;
  if (ws_size >= base_need + 32 * per_spl) {
    run_pipeline<32>(pw, pp, tw, tp, ipw, itw, ipp, itp, ws, out, stream);
  } else if (ws_size >= base_need + 16 * per_spl) {
    run_pipeline<16>(pw, pp, tw, tp, ipw, itw, ipp, itp, ws, out, stream);
  } else {
    run_pipeline<8>(pw, pp, tw, tp, ipw, itw, ipp, itp, ws, out, stream);
  }
}